// Round 1
// baseline (19933.809 us; speedup 1.0000x reference)
//
#include <hip/hip_runtime.h>
#include <math.h>

#define DIM      1024
#define K_GATES  24
#define NMAX     512          // max Chebyshev terms per gate
#define QUAD_M   2048         // quadrature points for Bessel J_n
#define BBOUND   66.0f        // spectral bound: GUE radius 64 + 3% margin
#define RPB      32           // rows per block
#define NBLOCKS  32           // 32 * 32 = 1024 rows
#define NTHREADS 512          // 8 waves of 64
#define PSLOT    8            // vector-slot ring depth (protocol needs >= 4)
#define CANARY   0x7FBADEAD7FBADEADull   // NaN|NaN payload: never a legit amplitude

union F2U { unsigned long long u; float2 f; };

// relaxed agent-scope (MALL-coherent) 8-byte ops — cross-XCD visible, no fences
__device__ __forceinline__ unsigned long long ld64coh(const unsigned long long* p) {
    return __hip_atomic_load(p, __ATOMIC_RELAXED, __HIP_MEMORY_SCOPE_AGENT);
}
__device__ __forceinline__ void st64coh(unsigned long long* p, unsigned long long v) {
    __hip_atomic_store(p, v, __ATOMIC_RELAXED, __HIP_MEMORY_SCOPE_AGENT);
}

// ---------------------------------------------------------------- init state
// slot0 = pad(feature,1024)/||feature||; slots 1..PSLOT-1 = CANARY
__global__ __launch_bounds__(1024) void init_state(const float* __restrict__ f,
                                                   int nfeat,
                                                   unsigned long long* __restrict__ slots) {
    __shared__ float red[16];
    __shared__ float invn_s;
    int t = threadIdx.x;
    float v = (t < nfeat) ? f[t] : 0.f;
    float s = v * v;
    #pragma unroll
    for (int o = 1; o < 64; o <<= 1) s += __shfl_xor(s, o);
    if ((t & 63) == 0) red[t >> 6] = s;
    __syncthreads();
    if (t == 0) {
        float tot = 0.f;
        for (int i = 0; i < 16; i++) tot += red[i];
        invn_s = 1.0f / sqrtf(tot);
    }
    __syncthreads();
    F2U c; c.f = make_float2(v * invn_s, 0.f);
    slots[t] = c.u;
    #pragma unroll
    for (int p = 1; p < PSLOT; p++) slots[(size_t)p * DIM + t] = CANARY;
}

// ---------------------------------------------------------------- Bessel coefs
// c_n(k) = (n==0?1:2) * (-i)^n * J_n(tau_k),  tau_k = theta_k * BBOUND
__global__ __launch_bounds__(256) void bessel_coef(const float* __restrict__ theta,
                                                   float2* __restrict__ coefs) {
    int n = blockIdx.x;   // 0..NMAX-1
    int k = blockIdx.y;   // 0..K_GATES-1
    double tau = (double)theta[k] * (double)BBOUND;
    int t = threadIdx.x;  // 256
    double acc = 0.0;
    #pragma unroll
    for (int i = 0; i < QUAD_M / 256; i++) {
        int j = t + 256 * i;
        double phi = (2.0 * M_PI / (double)QUAD_M) * (double)j;
        acc += cos((double)n * phi - tau * sin(phi));
    }
    #pragma unroll
    for (int o = 1; o < 64; o <<= 1) acc += __shfl_xor(acc, o);
    __shared__ double red[4];
    if ((t & 63) == 0) red[t >> 6] = acc;
    __syncthreads();
    if (t == 0) {
        double J = (red[0] + red[1] + red[2] + red[3]) / (double)QUAD_M;
        double f = (n == 0) ? 1.0 : 2.0;
        float cr = 0.f, cim = 0.f;
        switch (n & 3) {                 // (-i)^n
            case 0: cr  =  (float)(f * J); break;
            case 1: cim = -(float)(f * J); break;
            case 2: cr  = -(float)(f * J); break;
            case 3: cim =  (float)(f * J); break;
        }
        coefs[k * NMAX + n] = make_float2(cr, cim);
    }
}

// ---------------------------------------------------------------- truncation
__global__ __launch_bounds__(NMAX) void trunc_len(const float2* __restrict__ coefs,
                                                  int* __restrict__ nterm) {
    int k = blockIdx.x;
    int t = threadIdx.x;  // 512
    float2 c = coefs[k * NMAX + t];
    float mag = fabsf(c.x) + fabsf(c.y);
    int myn = (mag > 5e-7f) ? t : 0;
    #pragma unroll
    for (int o = 1; o < 64; o <<= 1) myn = max(myn, __shfl_xor(myn, o));
    __shared__ int red[8];
    if ((t & 63) == 0) red[t >> 6] = myn;
    __syncthreads();
    if (t == 0) {
        int m = 1;
        for (int i = 0; i < 8; i++) m = max(m, red[i]);
        nterm[k] = min(m, NMAX - 1);
    }
}

// ---------------------------------------------------------------- main kernel
//
// Barrier-free dataflow protocol (data-as-flag):
//  * Vector for global round rho lives in slots[rho % PSLOT]. Round rho:
//    consume slot[rho-1], publish slot[rho]. CANARY marks "not yet written".
//  * Invariant: a wave publishes round rho only after consuming ALL of rho-1.
//    Hence: observing full round rho-1  =>  every wave published rho-1
//           =>  every wave fully consumed rho-2  =>  slot[rho-2] is dead.
//    So each component's owner re-arms (CANARY) its comps of slot[rho-2]
//    right after finishing its round-rho consume.
//  * Slot reuse distance PSLOT=8; re-arm visibility is made transitive by the
//    per-round `s_waitcnt vmcnt(0)` (drains publish+re-arm at the single MALL
//    coherence point before the next round's publish can be observed).
//    Formal requirement is PSLOT >= 4.
//  * 32 blocks x 512 threads; wave owns 4 rows, Gtilde fragments in VGPRs:
//    g[rq][m] = Gtilde[row(rq)][lane + 64*m].  Lane's state row: q = lane&3.
__global__ __launch_bounds__(NTHREADS, 2) void evolve(
        const float* __restrict__ gre, const float* __restrict__ gim,
        unsigned long long* __restrict__ slots,
        const float2* __restrict__ coefs, const int* __restrict__ nterm,
        float* __restrict__ out) {
    __shared__ float2 Gs[16 * DIM];          // 128 KiB: one 16-row half-panel
    const int t = threadIdx.x, b = blockIdx.x;
    const int wave = t >> 6, lane = t & 63;
    const int q = lane & 3;
    const int r0 = b * RPB;
    const int myrow = r0 + 16 * (q >> 1) + 8 * (q & 1) + wave;
    const float hB = 0.5f / BBOUND;

    float2 g[4][16];                         // 128 VGPRs: this lane's G fragments
    float2 psi, acc, t_m1, t_m2;
    { F2U c; c.u = ld64coh(slots + myrow); psi = c.f; }
    // force psi read to complete before any publish can make round-1 observable
    // (guards against a delayed load snapshotting slot0 after a re-arm)
    asm volatile("s_waitcnt vmcnt(0)" ::: "memory");
    acc = t_m1 = t_m2 = make_float2(0.f, 0.f);

    int rho = 1;
    for (int k = 0; k < K_GATES; ++k) {
        const float* R = gre + (size_t)k * DIM * DIM;
        const float* I = gim + (size_t)k * DIM * DIM;

        // ---- stage Gtilde = ((R+R^T)/2 + i (I-I^T)/2)/B, two 16-row halves ----
        for (int h = 0; h < 2; ++h) {
            const int c0 = r0 + 16 * h;
            __syncthreads();   // prior half's register pulls done before overwrite
            // pass A: column panel, transposed into LDS
            #pragma unroll
            for (int rep = 0; rep < 2; ++rep) {
                const int i = t + 512 * rep;
                const float4* Rc = (const float4*)(R + (size_t)i * DIM + c0);
                const float4* Ic = (const float4*)(I + (size_t)i * DIM + c0);
                float4 ra0 = Rc[0], ra1 = Rc[1], ra2 = Rc[2], ra3 = Rc[3];
                float4 ia0 = Ic[0], ia1 = Ic[1], ia2 = Ic[2], ia3 = Ic[3];
                Gs[ 0 * DIM + i] = make_float2(hB * ra0.x, -hB * ia0.x);
                Gs[ 1 * DIM + i] = make_float2(hB * ra0.y, -hB * ia0.y);
                Gs[ 2 * DIM + i] = make_float2(hB * ra0.z, -hB * ia0.z);
                Gs[ 3 * DIM + i] = make_float2(hB * ra0.w, -hB * ia0.w);
                Gs[ 4 * DIM + i] = make_float2(hB * ra1.x, -hB * ia1.x);
                Gs[ 5 * DIM + i] = make_float2(hB * ra1.y, -hB * ia1.y);
                Gs[ 6 * DIM + i] = make_float2(hB * ra1.z, -hB * ia1.z);
                Gs[ 7 * DIM + i] = make_float2(hB * ra1.w, -hB * ia1.w);
                Gs[ 8 * DIM + i] = make_float2(hB * ra2.x, -hB * ia2.x);
                Gs[ 9 * DIM + i] = make_float2(hB * ra2.y, -hB * ia2.y);
                Gs[10 * DIM + i] = make_float2(hB * ra2.z, -hB * ia2.z);
                Gs[11 * DIM + i] = make_float2(hB * ra2.w, -hB * ia2.w);
                Gs[12 * DIM + i] = make_float2(hB * ra3.x, -hB * ia3.x);
                Gs[13 * DIM + i] = make_float2(hB * ra3.y, -hB * ia3.y);
                Gs[14 * DIM + i] = make_float2(hB * ra3.z, -hB * ia3.z);
                Gs[15 * DIM + i] = make_float2(hB * ra3.w, -hB * ia3.w);
            }
            __syncthreads();
            // pass B: row panel (coalesced), accumulate into LDS
            #pragma unroll
            for (int s = 0; s < 2; ++s) {
                const int lr = wave + 8 * s;
                const int grow = r0 + 16 * h + lr;
                const float4* Rr = (const float4*)(R + (size_t)grow * DIM);
                const float4* Ir = (const float4*)(I + (size_t)grow * DIM);
                float4* G4 = (float4*)(Gs + (size_t)lr * DIM);
                #pragma unroll
                for (int m = 0; m < 4; ++m) {
                    int i4 = lane + 64 * m;
                    float4 rv = Rr[i4], iv = Ir[i4];
                    float4 g0 = G4[2 * i4], g1 = G4[2 * i4 + 1];
                    g0.x += hB * rv.x; g0.y += hB * iv.x;
                    g0.z += hB * rv.y; g0.w += hB * iv.y;
                    g1.x += hB * rv.z; g1.y += hB * iv.z;
                    g1.z += hB * rv.w; g1.w += hB * iv.w;
                    G4[2 * i4] = g0; G4[2 * i4 + 1] = g1;
                }
            }
            __syncthreads();
            // pull this half's two rows into registers: rq = 2h+p <-> lr = wave+8p
            #pragma unroll
            for (int p = 0; p < 2; ++p) {
                const int lr = wave + 8 * p;
                #pragma unroll
                for (int m = 0; m < 16; ++m)
                    g[2 * h + p][m] = Gs[lr * DIM + lane + 64 * m];
            }
        }

        const int N = nterm[k];
        const float2* C = coefs + (size_t)k * NMAX;

        // term rounds n=1..N, plus one epilogue round (publish new psi)
        for (int n = 1; n <= N + 1; ++n, ++rho) {
            unsigned long long* src = slots + (size_t)((rho - 1) & (PSLOT - 1)) * DIM;
            unsigned long long* dst = slots + (size_t)(rho & (PSLOT - 1)) * DIM;
            unsigned long long* ra  = slots + (size_t)((rho - 2) & (PSLOT - 1)) * DIM;

            // ---- consume round rho-1 (data-as-flag; sweep re-polls stragglers) ----
            unsigned long long v[16];
            #pragma unroll
            for (int m = 0; m < 16; ++m) v[m] = ld64coh(src + lane + 64 * m);
            unsigned pend = 0u;
            #pragma unroll
            for (int m = 0; m < 16; ++m) pend |= (v[m] == CANARY) ? (1u << m) : 0u;
            while (pend) {
                #pragma unroll
                for (int m = 0; m < 16; ++m)
                    if (pend & (1u << m)) v[m] = ld64coh(src + lane + 64 * m);
                #pragma unroll
                for (int m = 0; m < 16; ++m)
                    if (v[m] != CANARY) pend &= ~(1u << m);
            }
            asm volatile("" ::: "memory");   // spins complete before re-arm issues

            // ---- re-arm slot rho-2 (provably dead now; see invariant above) ----
            if (lane < 4) st64coh(ra + myrow, CANARY);

            float2 pub;
            if (n <= N) {
                // w[rq] = Gtilde_row(rq) . x  — per-lane partials over 16 comps
                float sre0 = 0.f, sim0 = 0.f, sre1 = 0.f, sim1 = 0.f;
                float sre2 = 0.f, sim2 = 0.f, sre3 = 0.f, sim3 = 0.f;
                #pragma unroll
                for (int m = 0; m < 16; ++m) {
                    F2U c; c.u = v[m];
                    const float xr = c.f.x, xi = c.f.y;
                    sre0 += g[0][m].x * xr - g[0][m].y * xi;
                    sim0 += g[0][m].x * xi + g[0][m].y * xr;
                    sre1 += g[1][m].x * xr - g[1][m].y * xi;
                    sim1 += g[1][m].x * xi + g[1][m].y * xr;
                    sre2 += g[2][m].x * xr - g[2][m].y * xi;
                    sim2 += g[2][m].x * xi + g[2][m].y * xr;
                    sre3 += g[3][m].x * xr - g[3][m].y * xi;
                    sim3 += g[3][m].x * xi + g[3][m].y * xr;
                }
                #pragma unroll
                for (int o = 1; o < 64; o <<= 1) {
                    sre0 += __shfl_xor(sre0, o); sim0 += __shfl_xor(sim0, o);
                    sre1 += __shfl_xor(sre1, o); sim1 += __shfl_xor(sim1, o);
                    sre2 += __shfl_xor(sre2, o); sim2 += __shfl_xor(sim2, o);
                    sre3 += __shfl_xor(sre3, o); sim3 += __shfl_xor(sim3, o);
                }
                const float wre = (q == 0) ? sre0 : (q == 1) ? sre1 : (q == 2) ? sre2 : sre3;
                const float wim = (q == 0) ? sim0 : (q == 1) ? sim1 : (q == 2) ? sim2 : sim3;

                float2 tn;
                if (n == 1) {                       // T_0 = psi, T_1 = Gt psi
                    tn = make_float2(wre, wim);
                    const float2 c0 = C[0], c1 = C[1];
                    acc.x = c0.x * psi.x - c0.y * psi.y + c1.x * wre - c1.y * wim;
                    acc.y = c0.x * psi.y + c0.y * psi.x + c1.x * wim + c1.y * wre;
                    t_m2 = psi;
                } else {                            // T_n = 2 Gt T_{n-1} - T_{n-2}
                    tn = make_float2(2.f * wre - t_m2.x, 2.f * wim - t_m2.y);
                    const float2 cn = C[n];
                    acc.x += cn.x * tn.x - cn.y * tn.y;
                    acc.y += cn.x * tn.y + cn.y * tn.x;
                    t_m2 = t_m1;
                }
                t_m1 = tn;
                pub = tn;
            } else {
                pub = acc;                          // epilogue: new psi
                psi = acc;
            }

            if (lane < 4) { F2U c; c.f = pub; st64coh(dst + myrow, c.u); }
            // drain publish + re-arm at the coherence point; also a compiler fence
            // so no next-round load is hoisted above this round's protocol ops
            asm volatile("s_waitcnt vmcnt(0)" ::: "memory");
        }
    }

    // probs = |psi|^2
    if (lane < 4) out[myrow] = psi.x * psi.x + psi.y * psi.y;
}

// ---------------------------------------------------------------- launch
extern "C" void kernel_launch(void* const* d_in, const int* in_sizes, int n_in,
                              void* d_out, int out_size, void* d_ws, size_t ws_size,
                              hipStream_t stream) {
    const float* feat  = (const float*)d_in[0];   // 1000
    const float* theta = (const float*)d_in[1];   // 24
    const float* gre   = (const float*)d_in[2];   // 24*1024*1024
    const float* gim   = (const float*)d_in[3];

    // ws layout: slots[PSLOT][1024] u64 | coefs[24][512] float2 | nterm[24] int
    char* base = (char*)d_ws;
    unsigned long long* slots = (unsigned long long*)base;
    float2* coefs = (float2*)(base + (size_t)PSLOT * DIM * sizeof(unsigned long long));
    int*    nterm = (int*)(base + (size_t)PSLOT * DIM * sizeof(unsigned long long)
                           + (size_t)K_GATES * NMAX * sizeof(float2));
    float* outp = (float*)d_out;

    init_state<<<1, 1024, 0, stream>>>(feat, in_sizes[0], slots);
    bessel_coef<<<dim3(NMAX, K_GATES), 256, 0, stream>>>(theta, coefs);
    trunc_len<<<K_GATES, NMAX, 0, stream>>>(coefs, nterm);

    void* args[] = {(void*)&gre, (void*)&gim, (void*)&slots,
                    (void*)&coefs, (void*)&nterm, (void*)&outp};
    hipLaunchCooperativeKernel((void*)evolve, dim3(NBLOCKS), dim3(NTHREADS),
                               args, 0, stream);
}

// Round 2
// 8073.626 us; speedup vs baseline: 2.4690x; 2.4690x over previous
//
#include <hip/hip_runtime.h>
#include <math.h>

#define DIM      1024
#define K_GATES  24
#define NMAX     512          // max Chebyshev terms per gate
#define QUAD_M   2048         // quadrature points for Bessel J_n
#define BBOUND   66.0f        // spectral bound: GUE radius 64 + 3% margin
#define ROWS     16           // rows per block
#define NBLOCKS  64           // 64 * 16 = 1024 rows
#define NTHREADS 1024         // 16 waves of 64
#define PSLOT    8            // vector-slot ring depth (protocol needs >= 4)
#define CANARY   0x7FBADEAD7FBADEADull   // NaN|NaN payload: never a legit amplitude

union F2U { unsigned long long u; float2 f; };

// relaxed agent-scope (MALL-coherent) 8-byte ops — cross-XCD visible, no fences
__device__ __forceinline__ unsigned long long ld64coh(const unsigned long long* p) {
    return __hip_atomic_load(p, __ATOMIC_RELAXED, __HIP_MEMORY_SCOPE_AGENT);
}
__device__ __forceinline__ void st64coh(unsigned long long* p, unsigned long long v) {
    __hip_atomic_store(p, v, __ATOMIC_RELAXED, __HIP_MEMORY_SCOPE_AGENT);
}

// ---------------------------------------------------------------- init state
// slot0 = pad(feature,1024)/||feature||; slots 1..PSLOT-1 = CANARY
__global__ __launch_bounds__(1024) void init_state(const float* __restrict__ f,
                                                   int nfeat,
                                                   unsigned long long* __restrict__ slots) {
    __shared__ float red[16];
    __shared__ float invn_s;
    int t = threadIdx.x;
    float v = (t < nfeat) ? f[t] : 0.f;
    float s = v * v;
    #pragma unroll
    for (int o = 1; o < 64; o <<= 1) s += __shfl_xor(s, o);
    if ((t & 63) == 0) red[t >> 6] = s;
    __syncthreads();
    if (t == 0) {
        float tot = 0.f;
        for (int i = 0; i < 16; i++) tot += red[i];
        invn_s = 1.0f / sqrtf(tot);
    }
    __syncthreads();
    F2U c; c.f = make_float2(v * invn_s, 0.f);
    slots[t] = c.u;
    #pragma unroll
    for (int p = 1; p < PSLOT; p++) slots[(size_t)p * DIM + t] = CANARY;
}

// ---------------------------------------------------------------- Bessel coefs
// c_n(k) = (n==0?1:2) * (-i)^n * J_n(tau_k),  tau_k = theta_k * BBOUND
__global__ __launch_bounds__(256) void bessel_coef(const float* __restrict__ theta,
                                                   float2* __restrict__ coefs) {
    int n = blockIdx.x;   // 0..NMAX-1
    int k = blockIdx.y;   // 0..K_GATES-1
    double tau = (double)theta[k] * (double)BBOUND;
    int t = threadIdx.x;  // 256
    double acc = 0.0;
    #pragma unroll
    for (int i = 0; i < QUAD_M / 256; i++) {
        int j = t + 256 * i;
        double phi = (2.0 * M_PI / (double)QUAD_M) * (double)j;
        acc += cos((double)n * phi - tau * sin(phi));
    }
    #pragma unroll
    for (int o = 1; o < 64; o <<= 1) acc += __shfl_xor(acc, o);
    __shared__ double red[4];
    if ((t & 63) == 0) red[t >> 6] = acc;
    __syncthreads();
    if (t == 0) {
        double J = (red[0] + red[1] + red[2] + red[3]) / (double)QUAD_M;
        double f = (n == 0) ? 1.0 : 2.0;
        float cr = 0.f, cim = 0.f;
        switch (n & 3) {                 // (-i)^n
            case 0: cr  =  (float)(f * J); break;
            case 1: cim = -(float)(f * J); break;
            case 2: cr  = -(float)(f * J); break;
            case 3: cim =  (float)(f * J); break;
        }
        coefs[k * NMAX + n] = make_float2(cr, cim);
    }
}

// ---------------------------------------------------------------- truncation
__global__ __launch_bounds__(NMAX) void trunc_len(const float2* __restrict__ coefs,
                                                  int* __restrict__ nterm) {
    int k = blockIdx.x;
    int t = threadIdx.x;  // 512
    float2 c = coefs[k * NMAX + t];
    float mag = fabsf(c.x) + fabsf(c.y);
    int myn = (mag > 5e-7f) ? t : 0;
    #pragma unroll
    for (int o = 1; o < 64; o <<= 1) myn = max(myn, __shfl_xor(myn, o));
    __shared__ int red[8];
    if ((t & 63) == 0) red[t >> 6] = myn;
    __syncthreads();
    if (t == 0) {
        int m = 1;
        for (int i = 0; i < 8; i++) m = max(m, red[i]);
        nterm[k] = min(m, NMAX - 1);
    }
}

// ---------------------------------------------------------------- main kernel
//
// Data-as-flag exchange, one dependent poll per thread (the R1 fix):
//  * Vector for global round rho lives in slots[rho % PSLOT]; CANARY = "not
//    yet written". Round rho: thread t polls component t of slot[rho-1] with a
//    SINGLE dependent-chain load (self-throttled: 1 request per MALL RT per
//    thread), stages it to LDS, __syncthreads = "full vector arrived".
//  * Invariant: a block passes its round-rho syncthreads only after consuming
//    ALL of rho-1  =>  every block published rho-1  =>  every block passed its
//    round-(rho-1) syncthreads  =>  every block fully consumed rho-2  =>
//    slot[rho-2] is dead. So re-arm (CANARY) of the block's own 16 components
//    of slot[rho-2] goes right AFTER the syncthreads.
//  * Re-arm -> republish ordering: re-arm issued in round rho drains at the
//    round-(rho+1) syncthreads (vmcnt(0) before s_barrier); slot republished
//    at round rho+PSLOT-2 — ordered through the single MALL coherence point
//    with 6 rounds of slack (formal requirement PSLOT >= 4).
//  * Geometry identical to the proven 6.2ms kernel: 64 blocks x 1024 threads,
//    16 rows/block (one wave per row), G panel in LDS, dot from LDS xs.
__global__ __launch_bounds__(NTHREADS) void evolve(
        const float* __restrict__ gre, const float* __restrict__ gim,
        unsigned long long* __restrict__ slots,
        const float2* __restrict__ coefs, const int* __restrict__ nterm,
        float* __restrict__ out) {
    __shared__ float2 Gs[ROWS * DIM];        // 128 KiB: this block's 16 rows of Gtilde
    __shared__ float2 xs[2 * DIM];           // 16 KiB: double-buffered staged vector
    const int t = threadIdx.x, b = blockIdx.x;
    const int wave = t >> 6, lane = t & 63;
    const int r0 = b * ROWS;
    const int r = r0 + wave;                 // this wave's row (global component idx)
    const float hB = 0.5f / BBOUND;

    float2 acc = make_float2(0.f, 0.f);
    float2 t_m1 = acc, t_m2 = acc;
    int rho = 1;

    for (int k = 0; k < K_GATES; k++) {
        const float* R = gre + (size_t)k * DIM * DIM;
        const float* I = gim + (size_t)k * DIM * DIM;

        // ---- stage Gtilde = ((R+R^T)/2 + i (I-I^T)/2)/B into LDS ----
        // (safe to write Gs: every wave passed the previous round's syncthreads,
        //  which is after its last dot read of Gs)
        // pass A: column panel R[:, r0:r0+16], I[:, r0:r0+16] (64 B per row)
        {
            const float4* Rc = (const float4*)(R + (size_t)t * DIM + r0);
            const float4* Ic = (const float4*)(I + (size_t)t * DIM + r0);
            float4 ra0 = Rc[0], ra1 = Rc[1], ra2 = Rc[2], ra3 = Rc[3];
            float4 ia0 = Ic[0], ia1 = Ic[1], ia2 = Ic[2], ia3 = Ic[3];
            Gs[ 0 * DIM + t] = make_float2(hB * ra0.x, -hB * ia0.x);
            Gs[ 1 * DIM + t] = make_float2(hB * ra0.y, -hB * ia0.y);
            Gs[ 2 * DIM + t] = make_float2(hB * ra0.z, -hB * ia0.z);
            Gs[ 3 * DIM + t] = make_float2(hB * ra0.w, -hB * ia0.w);
            Gs[ 4 * DIM + t] = make_float2(hB * ra1.x, -hB * ia1.x);
            Gs[ 5 * DIM + t] = make_float2(hB * ra1.y, -hB * ia1.y);
            Gs[ 6 * DIM + t] = make_float2(hB * ra1.z, -hB * ia1.z);
            Gs[ 7 * DIM + t] = make_float2(hB * ra1.w, -hB * ia1.w);
            Gs[ 8 * DIM + t] = make_float2(hB * ra2.x, -hB * ia2.x);
            Gs[ 9 * DIM + t] = make_float2(hB * ra2.y, -hB * ia2.y);
            Gs[10 * DIM + t] = make_float2(hB * ra2.z, -hB * ia2.z);
            Gs[11 * DIM + t] = make_float2(hB * ra2.w, -hB * ia2.w);
            Gs[12 * DIM + t] = make_float2(hB * ra3.x, -hB * ia3.x);
            Gs[13 * DIM + t] = make_float2(hB * ra3.y, -hB * ia3.y);
            Gs[14 * DIM + t] = make_float2(hB * ra3.z, -hB * ia3.z);
            Gs[15 * DIM + t] = make_float2(hB * ra3.w, -hB * ia3.w);
        }
        __syncthreads();
        // pass B: row panel (coalesced), accumulate into LDS
        {
            const float4* Rr = (const float4*)(R + (size_t)r * DIM);
            const float4* Ir = (const float4*)(I + (size_t)r * DIM);
            float4* G4 = (float4*)(Gs + (size_t)wave * DIM);
            #pragma unroll
            for (int m = 0; m < 4; m++) {
                int i4 = lane + 64 * m;          // 256 float4 = 1024 floats
                float4 rv = Rr[i4], iv = Ir[i4];
                float4 g0 = G4[2 * i4], g1 = G4[2 * i4 + 1];
                g0.x += hB * rv.x; g0.y += hB * iv.x;
                g0.z += hB * rv.y; g0.w += hB * iv.y;
                g1.x += hB * rv.z; g1.y += hB * iv.z;
                g1.z += hB * rv.w; g1.w += hB * iv.w;
                G4[2 * i4] = g0; G4[2 * i4 + 1] = g1;
            }
        }
        __syncthreads();

        const int N = nterm[k];
        const float2* C = coefs + (size_t)k * NMAX;

        // term rounds n=1..N, plus one epilogue round (publish new psi = acc)
        for (int n = 1; n <= N + 1; ++n, ++rho) {
            unsigned long long* src = slots + (size_t)((rho - 1) & (PSLOT - 1)) * DIM;
            unsigned long long* dst = slots + (size_t)(rho & (PSLOT - 1)) * DIM;
            unsigned long long* ra  = slots + (size_t)((rho - 2) & (PSLOT - 1)) * DIM;
            float2* xsb = xs + (size_t)(rho & 1) * DIM;

            // ---- consume: thread t polls its own component (dependent chain) ----
            unsigned long long u = ld64coh(src + t);
            while (u == CANARY) u = ld64coh(src + t);
            { F2U c; c.u = u; xsb[t] = c.f; }
            __syncthreads();                     // full vector staged in LDS

            // ---- re-arm slot rho-2 (provably dead; see invariant above) ----
            if (t < ROWS) st64coh(ra + r0 + t, CANARY);

            float2 pub;
            if (n <= N) {
                // w = Gtilde_row . x  (complex dot over 1024, one wave per row)
                float sre = 0.f, sim = 0.f;
                const float4* x4 = (const float4*)xsb;
                const float4* g4 = (const float4*)(Gs + (size_t)wave * DIM);
                #pragma unroll
                for (int m = 0; m < 8; m++) {
                    int idx = lane + 64 * m;     // 512 float4 = 1024 complex
                    float4 xv = x4[idx];
                    float4 gv = g4[idx];
                    sre += gv.x * xv.x - gv.y * xv.y + gv.z * xv.z - gv.w * xv.w;
                    sim += gv.x * xv.y + gv.y * xv.x + gv.z * xv.w + gv.w * xv.z;
                }
                #pragma unroll
                for (int o = 1; o < 64; o <<= 1) {
                    sre += __shfl_xor(sre, o);
                    sim += __shfl_xor(sim, o);
                }

                float2 tn;
                if (n == 1) {                    // T_0 = psi (staged), T_1 = Gt psi
                    tn = make_float2(sre, sim);
                    float2 p0 = xsb[r];
                    const float2 c0 = C[0], c1 = C[1];
                    acc.x = c0.x * p0.x - c0.y * p0.y + c1.x * tn.x - c1.y * tn.y;
                    acc.y = c0.x * p0.y + c0.y * p0.x + c1.x * tn.y + c1.y * tn.x;
                    t_m2 = p0;
                } else {                         // T_n = 2 Gt T_{n-1} - T_{n-2}
                    tn = make_float2(2.f * sre - t_m2.x, 2.f * sim - t_m2.y);
                    const float2 cn = C[n];
                    acc.x += cn.x * tn.x - cn.y * tn.y;
                    acc.y += cn.x * tn.y + cn.y * tn.x;
                    t_m2 = t_m1;
                }
                t_m1 = tn;
                pub = tn;
            } else {
                pub = acc;                       // epilogue: new psi
            }

            if (lane == 0) { F2U c; c.f = pub; st64coh(dst + r, c.u); }
        }
    }

    // probs = |psi|^2 (acc holds this wave's row of the final state)
    if (lane == 0) out[r] = acc.x * acc.x + acc.y * acc.y;
}

// ---------------------------------------------------------------- launch
extern "C" void kernel_launch(void* const* d_in, const int* in_sizes, int n_in,
                              void* d_out, int out_size, void* d_ws, size_t ws_size,
                              hipStream_t stream) {
    const float* feat  = (const float*)d_in[0];   // 1000
    const float* theta = (const float*)d_in[1];   // 24
    const float* gre   = (const float*)d_in[2];   // 24*1024*1024
    const float* gim   = (const float*)d_in[3];

    // ws layout: slots[PSLOT][1024] u64 | coefs[24][512] float2 | nterm[24] int
    char* base = (char*)d_ws;
    unsigned long long* slots = (unsigned long long*)base;
    float2* coefs = (float2*)(base + (size_t)PSLOT * DIM * sizeof(unsigned long long));
    int*    nterm = (int*)(base + (size_t)PSLOT * DIM * sizeof(unsigned long long)
                           + (size_t)K_GATES * NMAX * sizeof(float2));
    float* outp = (float*)d_out;

    init_state<<<1, 1024, 0, stream>>>(feat, in_sizes[0], slots);
    bessel_coef<<<dim3(NMAX, K_GATES), 256, 0, stream>>>(theta, coefs);
    trunc_len<<<K_GATES, NMAX, 0, stream>>>(coefs, nterm);

    void* args[] = {(void*)&gre, (void*)&gim, (void*)&slots,
                    (void*)&coefs, (void*)&nterm, (void*)&outp};
    hipLaunchCooperativeKernel((void*)evolve, dim3(NBLOCKS), dim3(NTHREADS),
                               args, 0, stream);
}